// Round 6
// baseline (1439.989 us; speedup 1.0000x reference)
//
#include <hip/hip_runtime.h>

// out = sigmoid(alpha)[:,None] * 0.5 * (ax - x) + x0
// ax = segment_sum(adj_values[:,None] * x[adj_col], adj_row)
//
// R6: csr_gather was cache-state-invariant at 130us = L2/L3 random-row-gather
// ceiling (~6.8 TB/s effective on 819 MB of 512B-row reads). Structural fix:
//  (1) gather bf16 x (pre-cast once) -> halves gather bytes;
//  (2) drop row-level CSR: only bucket(128-row) grouping is needed. One block
//      per bucket keeps a 128x128 fp32 accumulator in 64KB LDS, streams its
//      contiguous UNSORTED epackA slice, LDS-atomicAdds val*x[col] per edge,
//      then fused epilogue out = s*(acc - x) + x0 (s = 0.5*sigmoid(alpha)).
// Eliminated: 100k hist, 3-kernel scan, bucket_sort, epackB.

#define RPB 128              // rows per bucket
#define NBMAX 1024           // max buckets (N <= 131072)
#define ACHUNK 4096          // edges per bin block

__device__ __forceinline__ float sigmoidf_(float a) {
    return 1.0f / (1.0f + __expf(-a));
}
__device__ __forceinline__ unsigned f2bf(float f) {   // fp32 -> bf16 (RNE)
    unsigned u = __float_as_uint(f);
    return (u + 0x7FFFu + ((u >> 16) & 1u)) >> 16;
}

// x (fp32) -> xb (bf16), 4 elements per thread
__global__ __launch_bounds__(256)
void xcast_kernel(const float* __restrict__ x, unsigned short* __restrict__ xb,
                  int n4) {
    int i = blockIdx.x * blockDim.x + threadIdx.x;
    if (i >= n4) return;
    float4 v = reinterpret_cast<const float4*>(x)[i];
    uint2 o;
    o.x = f2bf(v.x) | (f2bf(v.y) << 16);
    o.y = f2bf(v.z) | (f2bf(v.w) << 16);
    reinterpret_cast<uint2*>(xb)[i] = o;
}

// per-bucket histogram, LDS-staged
__global__ __launch_bounds__(256)
void bucket_hist_kernel(const int* __restrict__ row, int* __restrict__ bhist,
                        int n_edges, int nb) {
    __shared__ int h[NBMAX];
    int t = threadIdx.x;
    for (int i = t; i < nb; i += 256) h[i] = 0;
    __syncthreads();
    int n4 = n_edges >> 2;
    for (int i = blockIdx.x * blockDim.x + t; i < n4;
         i += gridDim.x * blockDim.x) {
        int4 r = reinterpret_cast<const int4*>(row)[i];
        atomicAdd(&h[r.x >> 7], 1);
        atomicAdd(&h[r.y >> 7], 1);
        atomicAdd(&h[r.z >> 7], 1);
        atomicAdd(&h[r.w >> 7], 1);
    }
    if (blockIdx.x == 0 && t == 0) {
        for (int i = n4 << 2; i < n_edges; ++i)
            atomicAdd(&bhist[row[i] >> 7], 1);
    }
    __syncthreads();
    for (int i = t; i < nb; i += 256)
        if (h[i]) atomicAdd(&bhist[i], h[i]);
}

// single-block exclusive scan of bhist[0..nb) -> boffs[0..nb], bcur copy
__global__ __launch_bounds__(1024)
void bucket_scan_kernel(const int* __restrict__ bhist, int* __restrict__ boffs,
                        int* __restrict__ bcur, int nb) {
    __shared__ int ts[1024];
    int t = threadIdx.x;
    ts[t] = (t < nb) ? bhist[t] : 0;
    __syncthreads();
    for (int off = 1; off < 1024; off <<= 1) {
        int u = (t >= off) ? ts[t - off] : 0;
        __syncthreads();
        ts[t] += u;
        __syncthreads();
    }
    if (t < nb) {
        int e = (t == 0) ? 0 : ts[t - 1];
        boffs[t] = e;
        bcur[t] = e;
    }
    if (t == nb - 1) boffs[nb] = ts[t];
}

// bin edges into RPB-row buckets, LDS-staged so global writes are runs of
// consecutive slots. epackA entry: ((localrow<<17)|col, valbits)
__global__ __launch_bounds__(256)
void bin_kernel(const int* __restrict__ row, const int* __restrict__ col,
                const float* __restrict__ vals, int* __restrict__ bcursor,
                int2* __restrict__ epackA, int n_edges, int nb) {
    __shared__ int hist[NBMAX];
    __shared__ int lbase[NBMAX];
    __shared__ int gbase[NBMAX];
    __shared__ int lcur[NBMAX];
    __shared__ int ts[256];
    __shared__ int2 stage[ACHUNK];
    __shared__ int gpos[ACHUNK];
    int t = threadIdx.x;
    int base = blockIdx.x * ACHUNK;
    int m = n_edges - base;
    if (m > ACHUNK) m = ACHUNK;
    for (int i = t; i < nb; i += 256) hist[i] = 0;
    __syncthreads();
    for (int i = t; i < m; i += 256)
        atomicAdd(&hist[row[base + i] >> 7], 1);
    __syncthreads();
    int tb = t * 4;
    int h0 = (tb + 0 < nb) ? hist[tb + 0] : 0;
    int h1 = (tb + 1 < nb) ? hist[tb + 1] : 0;
    int h2 = (tb + 2 < nb) ? hist[tb + 2] : 0;
    int h3 = (tb + 3 < nb) ? hist[tb + 3] : 0;
    int s0 = h0, s1 = s0 + h1, s2 = s1 + h2, s3 = s2 + h3;
    ts[t] = s3;
    __syncthreads();
    for (int off = 1; off < 256; off <<= 1) {
        int u = (t >= off) ? ts[t - off] : 0;
        __syncthreads();
        ts[t] += u;
        __syncthreads();
    }
    int ex = (t == 0) ? 0 : ts[t - 1];
    if (tb + 0 < nb) lbase[tb + 0] = ex;
    if (tb + 1 < nb) lbase[tb + 1] = ex + s0;
    if (tb + 2 < nb) lbase[tb + 2] = ex + s1;
    if (tb + 3 < nb) lbase[tb + 3] = ex + s2;
    __syncthreads();
    for (int i = t; i < nb; i += 256) {
        gbase[i] = atomicAdd(&bcursor[i], hist[i]);
        lcur[i] = 0;
    }
    __syncthreads();
    for (int i = t; i < m; i += 256) {
        int r = row[base + i];
        int c = col[base + i];
        float v = vals[base + i];
        int bk = r >> 7;
        int lp = atomicAdd(&lcur[bk], 1);
        int sp = lbase[bk] + lp;
        stage[sp] = make_int2(((r & (RPB - 1)) << 17) | c, __float_as_int(v));
        gpos[sp] = gbase[bk] + lp;
    }
    __syncthreads();
    for (int i = t; i < m; i += 256)
        epackA[gpos[i]] = stage[i];
}

// one block per bucket: 128x128 fp32 LDS accumulator; stream the bucket's
// contiguous (unsorted) epackA slice; per edge one wave gathers the source
// row (bf16: 1 dword/lane, fp32: float2/lane), 8-deep pipelined, and does
// 2 LDS float atomicAdds per lane. Fused epilogue: out = s*(acc-x)+x0.
template <int USE_BF16>
__global__ __launch_bounds__(512)
void bucket_acc_kernel(const unsigned short* __restrict__ xb,
                       const float* __restrict__ x,
                       const float* __restrict__ x0,
                       const float* __restrict__ alpha,
                       const int* __restrict__ boffs,
                       const int2* __restrict__ ep,
                       float* __restrict__ out, int n_nodes) {
    extern __shared__ float acc[];          // RPB*128 floats = 64 KB
    int t = threadIdx.x, wave = t >> 6, lane = t & 63;
    for (int i = t * 4; i < RPB * 128; i += 512 * 4)
        *reinterpret_cast<float4*>(acc + i) = make_float4(0.f, 0.f, 0.f, 0.f);
    __syncthreads();
    int b = blockIdx.x;
    int beg = boffs[b], end = boffs[b + 1];
    for (int cb = beg + wave * 64; cb < end; cb += 512) {
        int m = end - cb;
        if (m > 64) m = 64;
        int2 e = (lane < m) ? ep[cb + lane] : make_int2(0, 0);
        int k = 0;
        for (; k + 8 <= m; k += 8) {
            int lr[8]; float w[8];
            if (USE_BF16) {
                unsigned d[8];
#pragma unroll
                for (int j = 0; j < 8; ++j) {
                    int exx = __shfl(e.x, k + j);
                    int eyy = __shfl(e.y, k + j);
                    lr[j] = exx >> 17;
                    w[j] = __int_as_float(eyy);
                    d[j] = reinterpret_cast<const unsigned*>(
                        xb + (size_t)(exx & 0x1FFFF) * 128)[lane];
                }
#pragma unroll
                for (int j = 0; j < 8; ++j) {
                    float f0 = __uint_as_float((d[j] & 0xFFFFu) << 16);
                    float f1 = __uint_as_float(d[j] & 0xFFFF0000u);
                    float* p = acc + lr[j] * 128 + lane * 2;
                    atomicAdd(p + 0, w[j] * f0);
                    atomicAdd(p + 1, w[j] * f1);
                }
            } else {
                float2 v[8];
#pragma unroll
                for (int j = 0; j < 8; ++j) {
                    int exx = __shfl(e.x, k + j);
                    int eyy = __shfl(e.y, k + j);
                    lr[j] = exx >> 17;
                    w[j] = __int_as_float(eyy);
                    v[j] = reinterpret_cast<const float2*>(
                        x + (size_t)(exx & 0x1FFFF) * 128)[lane];
                }
#pragma unroll
                for (int j = 0; j < 8; ++j) {
                    float* p = acc + lr[j] * 128 + lane * 2;
                    atomicAdd(p + 0, w[j] * v[j].x);
                    atomicAdd(p + 1, w[j] * v[j].y);
                }
            }
        }
        for (; k < m; ++k) {
            int exx = __shfl(e.x, k);
            int eyy = __shfl(e.y, k);
            int lr = exx >> 17;
            float w = __int_as_float(eyy);
            float f0, f1;
            if (USE_BF16) {
                unsigned d = reinterpret_cast<const unsigned*>(
                    xb + (size_t)(exx & 0x1FFFF) * 128)[lane];
                f0 = __uint_as_float((d & 0xFFFFu) << 16);
                f1 = __uint_as_float(d & 0xFFFF0000u);
            } else {
                float2 v = reinterpret_cast<const float2*>(
                    x + (size_t)(exx & 0x1FFFF) * 128)[lane];
                f0 = v.x; f1 = v.y;
            }
            float* p = acc + lr * 128 + lane * 2;
            atomicAdd(p + 0, w * f0);
            atomicAdd(p + 1, w * f1);
        }
    }
    __syncthreads();
    int r0 = b * RPB;
    for (int lrr = wave; lrr < RPB; lrr += 8) {
        int r = r0 + lrr;
        if (r >= n_nodes) break;
        float s = 0.5f * sigmoidf_(alpha[r]);
        float2 a = *reinterpret_cast<float2*>(acc + lrr * 128 + lane * 2);
        float2 xv = reinterpret_cast<const float2*>(x + (size_t)r * 128)[lane];
        float2 x0v = reinterpret_cast<const float2*>(x0 + (size_t)r * 128)[lane];
        float2 o;
        o.x = s * (a.x - xv.x) + x0v.x;
        o.y = s * (a.y - xv.y) + x0v.y;
        reinterpret_cast<float2*>(out + (size_t)r * 128)[lane] = o;
    }
}

extern "C" void kernel_launch(void* const* d_in, const int* in_sizes, int n_in,
                              void* d_out, int out_size, void* d_ws, size_t ws_size,
                              hipStream_t stream) {
    // inputs: 0=t(unused), 1=x[N,D], 2=x0[N,D], 3=alpha[N], 4=vals[E],
    //         5=row[E](i32), 6=col[E](i32)
    const float* x     = (const float*)d_in[1];
    const float* x0    = (const float*)d_in[2];
    const float* alpha = (const float*)d_in[3];
    const float* vals  = (const float*)d_in[4];
    const int*   row   = (const int*)d_in[5];
    const int*   col   = (const int*)d_in[6];
    float* out = (float*)d_out;

    int n_nodes = in_sizes[3];
    int n_edges = in_sizes[4];
    int nb = (n_nodes + RPB - 1) / RPB;            // 782 buckets

    // workspace layout
    int*  bhist = (int*)d_ws;                      // NBMAX
    int*  boffs = bhist + NBMAX;                   // NBMAX+1 (pad to NBMAX+16)
    int*  bcur  = boffs + NBMAX + 16;              // NBMAX
    char* p     = (char*)(bcur + NBMAX);
    size_t base_bytes = (size_t)(p - (char*)d_ws);
    size_t xb_bytes = (size_t)n_nodes * 128 * sizeof(unsigned short);
    size_t ep_bytes = (size_t)n_edges * sizeof(int2);
    int use_bf16 = (ws_size >= base_bytes + xb_bytes + ep_bytes + 256) ? 1 : 0;

    unsigned short* xxb = (unsigned short*)p;
    int2* epackA = use_bf16 ? (int2*)(p + ((xb_bytes + 255) & ~(size_t)255))
                            : (int2*)p;

    hipMemsetAsync(bhist, 0, NBMAX * sizeof(int), stream);

    if (use_bf16) {
        int n4 = (n_nodes * 128) >> 2;             // D=128 divisible by 4
        xcast_kernel<<<(n4 + 255) / 256, 256, 0, stream>>>(x, xxb, n4);
    }
    bucket_hist_kernel<<<256, 256, 0, stream>>>(row, bhist, n_edges, nb);
    bucket_scan_kernel<<<1, 1024, 0, stream>>>(bhist, boffs, bcur, nb);
    {
        int grid = (n_edges + ACHUNK - 1) / ACHUNK;
        bin_kernel<<<grid, 256, 0, stream>>>(row, col, vals, bcur, epackA,
                                             n_edges, nb);
    }
    if (use_bf16) {
        bucket_acc_kernel<1><<<nb, 512, RPB * 128 * sizeof(float), stream>>>(
            xxb, x, x0, alpha, boffs, epackA, out, n_nodes);
    } else {
        bucket_acc_kernel<0><<<nb, 512, RPB * 128 * sizeof(float), stream>>>(
            xxb, x, x0, alpha, boffs, epackA, out, n_nodes);
    }
}

// Round 7
// 206.274 us; speedup vs baseline: 6.9809x; 6.9809x over previous
//
#include <hip/hip_runtime.h>

// out = sigmoid(alpha)[:,None] * 0.5 * (ax - x) + x0
// ax = segment_sum(adj_values[:,None] * x[adj_col], adj_row)
//
// R7: R6's LDS-atomic accumulate was a disaster (204.8M ds-atomic RMWs,
// 1405us). Revert to R5's register-accumulate CSR gather (proven 130us),
// keep R6's only validated win: gather from a bf16 copy of x (halves the
// random-row line traffic; absmax 0.031 << 0.15 threshold, proven in R6).
// Bucket sort is now IN-PLACE (LDS-staged per-bucket scatter) so workspace
// fits: meta + xb(25.6MB) + epackA(12.8MB). fp32 fallback if ws too small.

#define DIM 128
#define TILE 1024            // elements per scan block (256 thr x int4)
#define RPB 128              // rows per bucket (power of 2)
#define ACHUNK 4096          // edges per bin block
#define BCAP 4096            // in-place bucket sort LDS capacity (entries)
#define NBMAX 1024           // max buckets

__device__ __forceinline__ float sigmoidf_(float a) {
    return 1.0f / (1.0f + __expf(-a));
}
__device__ __forceinline__ unsigned f2bf(float f) {   // fp32 -> bf16 (RNE)
    unsigned u = __float_as_uint(f);
    return (u + 0x7FFFu + ((u >> 16) & 1u)) >> 16;
}

// x (fp32) -> xb (bf16), 4 elements per thread
__global__ __launch_bounds__(256)
void xcast_kernel(const float* __restrict__ x, unsigned short* __restrict__ xb,
                  int n4) {
    int i = blockIdx.x * blockDim.x + threadIdx.x;
    if (i >= n4) return;
    float4 v = reinterpret_cast<const float4*>(x)[i];
    uint2 o;
    o.x = f2bf(v.x) | (f2bf(v.y) << 16);
    o.y = f2bf(v.z) | (f2bf(v.w) << 16);
    reinterpret_cast<uint2*>(xb)[i] = o;
}

// counts[row[e]]++ over all edges, 4 edges per thread
__global__ void hist_kernel(const int* __restrict__ row, int* __restrict__ counts,
                            int n_edges) {
    int n4 = n_edges >> 2;
    for (int i = blockIdx.x * blockDim.x + threadIdx.x; i < n4;
         i += gridDim.x * blockDim.x) {
        int4 r = reinterpret_cast<const int4*>(row)[i];
        atomicAdd(&counts[r.x], 1);
        atomicAdd(&counts[r.y], 1);
        atomicAdd(&counts[r.z], 1);
        atomicAdd(&counts[r.w], 1);
    }
    if (blockIdx.x == 0 && threadIdx.x == 0) {
        for (int i = n4 << 2; i < n_edges; ++i) atomicAdd(&counts[row[i]], 1);
    }
}

// per-block exclusive scan over TILE elements; write partial offsets + block sum
__global__ __launch_bounds__(256)
void scan_partial_kernel(const int* __restrict__ counts,
                         int* __restrict__ partial,
                         int* __restrict__ blocksums, int n) {
    __shared__ int ts[256];
    int t = threadIdx.x;
    int base = blockIdx.x * TILE + t * 4;
    int4 v = make_int4(0, 0, 0, 0);
    if (base + 3 < n) {
        v = *reinterpret_cast<const int4*>(counts + base);
    } else {
        if (base + 0 < n) v.x = counts[base + 0];
        if (base + 1 < n) v.y = counts[base + 1];
        if (base + 2 < n) v.z = counts[base + 2];
        if (base + 3 < n) v.w = counts[base + 3];
    }
    int s0 = v.x, s1 = s0 + v.y, s2 = s1 + v.z, s3 = s2 + v.w;
    ts[t] = s3;
    __syncthreads();
    for (int off = 1; off < 256; off <<= 1) {
        int u = (t >= off) ? ts[t - off] : 0;
        __syncthreads();
        ts[t] += u;
        __syncthreads();
    }
    int texcl = (t == 0) ? 0 : ts[t - 1];
    if (t == 255) blocksums[blockIdx.x] = ts[255];
    int4 o;
    o.x = texcl;
    o.y = texcl + s0;
    o.z = texcl + s1;
    o.w = texcl + s2;
    if (base + 3 < n) {
        *reinterpret_cast<int4*>(partial + base) = o;
    } else {
        if (base + 0 < n) partial[base + 0] = o.x;
        if (base + 1 < n) partial[base + 1] = o.y;
        if (base + 2 < n) partial[base + 2] = o.z;
        if (base + 3 < n) partial[base + 3] = o.w;
    }
}

// exclusive scan of blocksums[0..nb) in place (nb <= 1024)
__global__ __launch_bounds__(1024)
void scan_blocksums_kernel(int* __restrict__ blocksums, int nb) {
    __shared__ int ts[1024];
    int t = threadIdx.x;
    ts[t] = (t < nb) ? blocksums[t] : 0;
    __syncthreads();
    for (int off = 1; off < 1024; off <<= 1) {
        int u = (t >= off) ? ts[t - off] : 0;
        __syncthreads();
        ts[t] += u;
        __syncthreads();
    }
    if (t < nb) blocksums[t] = (t == 0) ? 0 : ts[t - 1];
}

// offsets = partial + blockbase; also emit bucket cursors at RPB boundaries
__global__ __launch_bounds__(256)
void add_base_kernel(int* __restrict__ offsets,
                     int* __restrict__ bcursor,
                     const int* __restrict__ blocksums, int n) {
    int bb = blocksums[blockIdx.x];
    int base = blockIdx.x * TILE + threadIdx.x * 4;
    if (base + 3 < n) {
        int4 v = *reinterpret_cast<const int4*>(offsets + base);
        v.x += bb; v.y += bb; v.z += bb; v.w += bb;
        *reinterpret_cast<int4*>(offsets + base) = v;
        if ((base & (RPB - 1)) == 0) bcursor[base >> 7] = v.x;  // RPB=128
    } else {
        for (int k = 0; k < 4; ++k) {
            if (base + k < n) {
                int v = offsets[base + k] + bb;
                offsets[base + k] = v;
                if (((base + k) & (RPB - 1)) == 0) bcursor[(base + k) >> 7] = v;
            }
        }
    }
}

// Phase A: bin edges into RPB-row buckets, LDS-staged so global writes are
// runs of consecutive slots. epackA entry: ((localrow<<17)|col, valbits)
__global__ __launch_bounds__(256)
void bin_kernel(const int* __restrict__ row, const int* __restrict__ col,
                const float* __restrict__ vals, int* __restrict__ bcursor,
                int2* __restrict__ epackA, int n_edges, int nb) {
    __shared__ int hist[NBMAX];
    __shared__ int lbase[NBMAX];
    __shared__ int gbase[NBMAX];
    __shared__ int lcur[NBMAX];
    __shared__ int ts[256];
    __shared__ int2 stage[ACHUNK];
    __shared__ int gpos[ACHUNK];
    int t = threadIdx.x;
    int base = blockIdx.x * ACHUNK;
    int m = n_edges - base;
    if (m > ACHUNK) m = ACHUNK;
    for (int i = t; i < nb; i += 256) hist[i] = 0;
    __syncthreads();
    for (int i = t; i < m; i += 256)
        atomicAdd(&hist[row[base + i] >> 7], 1);
    __syncthreads();
    int tb = t * 4;
    int h0 = (tb + 0 < nb) ? hist[tb + 0] : 0;
    int h1 = (tb + 1 < nb) ? hist[tb + 1] : 0;
    int h2 = (tb + 2 < nb) ? hist[tb + 2] : 0;
    int h3 = (tb + 3 < nb) ? hist[tb + 3] : 0;
    int s0 = h0, s1 = s0 + h1, s2 = s1 + h2, s3 = s2 + h3;
    ts[t] = s3;
    __syncthreads();
    for (int off = 1; off < 256; off <<= 1) {
        int u = (t >= off) ? ts[t - off] : 0;
        __syncthreads();
        ts[t] += u;
        __syncthreads();
    }
    int ex = (t == 0) ? 0 : ts[t - 1];
    if (tb + 0 < nb) lbase[tb + 0] = ex;
    if (tb + 1 < nb) lbase[tb + 1] = ex + s0;
    if (tb + 2 < nb) lbase[tb + 2] = ex + s1;
    if (tb + 3 < nb) lbase[tb + 3] = ex + s2;
    __syncthreads();
    for (int i = t; i < nb; i += 256) {
        gbase[i] = atomicAdd(&bcursor[i], hist[i]);
        lcur[i] = 0;
    }
    __syncthreads();
    for (int i = t; i < m; i += 256) {
        int r = row[base + i];
        int c = col[base + i];
        float v = vals[base + i];
        int bk = r >> 7;
        int lp = atomicAdd(&lcur[bk], 1);
        int sp = lbase[bk] + lp;
        stage[sp] = make_int2(((r & (RPB - 1)) << 17) | c, __float_as_int(v));
        gpos[sp] = gbase[bk] + lp;
    }
    __syncthreads();
    for (int i = t; i < m; i += 256)
        epackA[gpos[i]] = stage[i];
}

// Phase B: one block per bucket, IN-PLACE: load bucket slice to LDS, scatter
// to CSR order in LDS via row cursors (stripping localrow), stream back.
// Overflow (>BCAP, can't occur for this input) goes via global scratch.
__global__ __launch_bounds__(256)
void bucket_sort_kernel(const int* __restrict__ offsets,
                        int2* __restrict__ epackA,
                        int2* __restrict__ scratch,
                        int n_nodes, int n_edges) {
    __shared__ int2 ein[BCAP];
    __shared__ int2 eout[BCAP];
    __shared__ int rowcur[RPB];
    int b = blockIdx.x;
    int t = threadIdx.x;
    int r0 = b * RPB;
    int begin = offsets[r0];
    int rend = r0 + RPB;
    int end = (rend < n_nodes) ? offsets[rend] : n_edges;
    int n = end - begin;
    if (t < RPB) {
        int rr = r0 + t;
        rowcur[t] = (rr < n_nodes) ? (offsets[rr] - begin) : 0;
    }
    __syncthreads();
    if (n <= BCAP) {
        for (int i = t; i < n; i += 256) ein[i] = epackA[begin + i];
        __syncthreads();
        for (int i = t; i < n; i += 256) {
            int2 e = ein[i];
            int lr = e.x >> 17;
            int pos = atomicAdd(&rowcur[lr], 1);
            eout[pos] = make_int2(e.x & 0x1FFFF, e.y);
        }
        __syncthreads();
        for (int i = t; i < n; i += 256) epackA[begin + i] = eout[i];
    } else {
        // slow-correct fallback: scatter to scratch slice, then copy back
        for (int cbase = 0; cbase < n; cbase += BCAP) {
            int cm = n - cbase; if (cm > BCAP) cm = BCAP;
            for (int i = t; i < cm; i += 256) ein[i] = epackA[begin + cbase + i];
            __syncthreads();
            for (int i = t; i < cm; i += 256) {
                int2 e = ein[i];
                int lr = e.x >> 17;
                int pos = atomicAdd(&rowcur[lr], 1);
                scratch[begin + pos] = make_int2(e.x & 0x1FFFF, e.y);
            }
            __syncthreads();
        }
        for (int i = t; i < n; i += 256) epackA[begin + i] = scratch[begin + i];
    }
}

// wave per row; lane owns 2 columns. Edge metadata loaded lane-parallel,
// broadcast via __shfl; bf16 source rows (1 dword/lane), 8-deep pipelined.
__global__ __launch_bounds__(256)
void csr_gather_bf16_kernel(const unsigned short* __restrict__ xb,
                            const float* __restrict__ x,
                            const float* __restrict__ x0,
                            const float* __restrict__ alpha,
                            const int* __restrict__ offsets,
                            const int2* __restrict__ epack,
                            float* __restrict__ out, int n_nodes, int n_edges) {
    int gid = blockIdx.x * blockDim.x + threadIdx.x;
    int r = gid >> 6;
    int lane = gid & 63;
    if (r >= n_nodes) return;
    float s = 0.5f * sigmoidf_(alpha[r]);
    const unsigned* xbp = reinterpret_cast<const unsigned*>(xb);  // row stride 64
    int rb = r * 64;
    float2 xv = reinterpret_cast<const float2*>(x)[rb + lane];
    float2 acc = reinterpret_cast<const float2*>(x0)[rb + lane];
    acc.x -= s * xv.x;
    acc.y -= s * xv.y;
    int beg = offsets[r];
    int stop = (r + 1 < n_nodes) ? offsets[r + 1] : n_edges;
    for (int chunk = beg; chunk < stop; chunk += 64) {
        int m = stop - chunk;
        if (m > 64) m = 64;
        int2 e = (lane < m) ? epack[chunk + lane] : make_int2(0, 0);
        int k = 0;
        for (; k + 8 <= m; k += 8) {
            unsigned d[8]; float w[8];
#pragma unroll
            for (int j = 0; j < 8; ++j) {
                int c = __shfl(e.x, k + j);
                w[j] = s * __int_as_float(__shfl(e.y, k + j));
                d[j] = xbp[(size_t)c * 64 + lane];
            }
#pragma unroll
            for (int j = 0; j < 8; ++j) {
                acc.x += w[j] * __uint_as_float((d[j] & 0xFFFFu) << 16);
                acc.y += w[j] * __uint_as_float(d[j] & 0xFFFF0000u);
            }
        }
        for (; k < m; ++k) {
            int c = __shfl(e.x, k);
            float w = s * __int_as_float(__shfl(e.y, k));
            unsigned d = xbp[(size_t)c * 64 + lane];
            acc.x += w * __uint_as_float((d & 0xFFFFu) << 16);
            acc.y += w * __uint_as_float(d & 0xFFFF0000u);
        }
    }
    reinterpret_cast<float2*>(out)[rb + lane] = acc;
}

// fp32 fallback gather (R5 kernel, 4-wide)
__global__ __launch_bounds__(256)
void csr_gather_f32_kernel(const float* __restrict__ x,
                           const float* __restrict__ x0,
                           const float* __restrict__ alpha,
                           const int* __restrict__ offsets,
                           const int2* __restrict__ epack,
                           float* __restrict__ out, int n_nodes, int n_edges) {
    int gid = blockIdx.x * blockDim.x + threadIdx.x;
    int r = gid >> 6;
    int lane = gid & 63;
    if (r >= n_nodes) return;
    float s = 0.5f * sigmoidf_(alpha[r]);
    const float2* xp = reinterpret_cast<const float2*>(x);
    int rb = r * 64;
    float2 xv = xp[rb + lane];
    float2 acc = reinterpret_cast<const float2*>(x0)[rb + lane];
    acc.x -= s * xv.x;
    acc.y -= s * xv.y;
    int beg = offsets[r];
    int stop = (r + 1 < n_nodes) ? offsets[r + 1] : n_edges;
    for (int chunk = beg; chunk < stop; chunk += 64) {
        int m = stop - chunk;
        if (m > 64) m = 64;
        int2 e = (lane < m) ? epack[chunk + lane] : make_int2(0, 0);
        int k = 0;
        for (; k + 4 <= m; k += 4) {
            int c0 = __shfl(e.x, k + 0);
            int c1 = __shfl(e.x, k + 1);
            int c2 = __shfl(e.x, k + 2);
            int c3 = __shfl(e.x, k + 3);
            float w0 = s * __int_as_float(__shfl(e.y, k + 0));
            float w1 = s * __int_as_float(__shfl(e.y, k + 1));
            float w2 = s * __int_as_float(__shfl(e.y, k + 2));
            float w3 = s * __int_as_float(__shfl(e.y, k + 3));
            float2 v0 = xp[(size_t)c0 * 64 + lane];
            float2 v1 = xp[(size_t)c1 * 64 + lane];
            float2 v2 = xp[(size_t)c2 * 64 + lane];
            float2 v3 = xp[(size_t)c3 * 64 + lane];
            acc.x += w0 * v0.x; acc.y += w0 * v0.y;
            acc.x += w1 * v1.x; acc.y += w1 * v1.y;
            acc.x += w2 * v2.x; acc.y += w2 * v2.y;
            acc.x += w3 * v3.x; acc.y += w3 * v3.y;
        }
        for (; k < m; ++k) {
            int c = __shfl(e.x, k);
            float w = s * __int_as_float(__shfl(e.y, k));
            float2 v = xp[(size_t)c * 64 + lane];
            acc.x += w * v.x;
            acc.y += w * v.y;
        }
    }
    reinterpret_cast<float2*>(out)[rb + lane] = acc;
}

extern "C" void kernel_launch(void* const* d_in, const int* in_sizes, int n_in,
                              void* d_out, int out_size, void* d_ws, size_t ws_size,
                              hipStream_t stream) {
    // inputs: 0=t(unused), 1=x[N,D], 2=x0[N,D], 3=alpha[N], 4=vals[E],
    //         5=row[E](i32), 6=col[E](i32)
    const float* x     = (const float*)d_in[1];
    const float* x0    = (const float*)d_in[2];
    const float* alpha = (const float*)d_in[3];
    const float* vals  = (const float*)d_in[4];
    const int*   row   = (const int*)d_in[5];
    const int*   col   = (const int*)d_in[6];
    float* out = (float*)d_out;

    int n_nodes = in_sizes[3];
    int n_edges = in_sizes[4];
    int nblocks = (n_nodes + TILE - 1) / TILE;     // scan blocks
    int nb = (n_nodes + RPB - 1) / RPB;            // buckets (782)

    // workspace layout
    size_t npad = (size_t)((n_nodes + 3) & ~3);
    int*  counts    = (int*)d_ws;
    int*  offsets   = counts + npad;
    int*  blocksums = offsets + npad;              // 1024
    int*  bcursor   = blocksums + 1024;            // NBMAX
    char* p         = (char*)(bcursor + NBMAX);
    size_t base_bytes = (size_t)(p - (char*)d_ws);
    size_t xb_bytes = (size_t)n_nodes * DIM * sizeof(unsigned short);
    size_t ep_bytes = (size_t)((n_edges + 3) & ~3) * sizeof(int2);
    // bf16 layout: [xb 25.6MB][epackA 12.8MB]; sort-overflow scratch = xb tail
    int use_bf16 = (ws_size >= base_bytes + xb_bytes + ep_bytes + 256) ? 1 : 0;

    unsigned short* xxb;
    int2* epackA;
    int2* scratch;
    if (use_bf16) {
        xxb = (unsigned short*)p;
        epackA = (int2*)(p + ((xb_bytes + 255) & ~(size_t)255));
        scratch = (int2*)(p + ep_bytes);   // inside xb region, used pre-xcast
    } else {
        xxb = nullptr;
        epackA = (int2*)p;
        scratch = epackA + ((n_edges + 3) & ~3);
    }

    hipMemsetAsync(counts, 0, npad * sizeof(int), stream);

    {
        int block = 256;
        int grid = ((n_edges >> 2) + block - 1) / block;
        if (grid > 4096) grid = 4096;
        hist_kernel<<<grid, block, 0, stream>>>(row, counts, n_edges);
    }
    scan_partial_kernel<<<nblocks, 256, 0, stream>>>(counts, offsets,
                                                     blocksums, n_nodes);
    scan_blocksums_kernel<<<1, 1024, 0, stream>>>(blocksums, nblocks);
    add_base_kernel<<<nblocks, 256, 0, stream>>>(offsets, bcursor, blocksums,
                                                 n_nodes);
    {
        int grid = (n_edges + ACHUNK - 1) / ACHUNK;
        bin_kernel<<<grid, 256, 0, stream>>>(row, col, vals, bcursor, epackA,
                                             n_edges, nb);
    }
    bucket_sort_kernel<<<nb, 256, 0, stream>>>(offsets, epackA, scratch,
                                               n_nodes, n_edges);
    {
        long long total = (long long)n_nodes * 64;
        int block = 256;
        int grid = (int)((total + block - 1) / block);
        if (use_bf16) {
            int n4 = (n_nodes * DIM) >> 2;
            xcast_kernel<<<(n4 + 255) / 256, 256, 0, stream>>>(x, xxb, n4);
            csr_gather_bf16_kernel<<<grid, block, 0, stream>>>(
                xxb, x, x0, alpha, offsets, epackA, out, n_nodes, n_edges);
        } else {
            csr_gather_f32_kernel<<<grid, block, 0, stream>>>(
                x, x0, alpha, offsets, epackA, out, n_nodes, n_edges);
        }
    }
}

// Round 8
// 164.555 us; speedup vs baseline: 8.7508x; 1.2535x over previous
//
#include <hip/hip_runtime.h>

// out = sigmoid(alpha)[:,None] * 0.5 * (ax - x) + x0
// ax = segment_sum(adj_values[:,None] * x[adj_col], adj_row)
//
// R8: R7's gather (82us, bf16, register-accumulate) kept as-is. Preprocessing
// (124us) restructured to bucket granularity only: row-level hist/scan/memset
// (global, ~90us) deleted; per-row offsets are now computed INSIDE bucket_sort
// from a local 128-row LDS histogram + scan (rows only need grouping within
// their own bucket). Pipeline: bhist(782) -> bscan -> bin -> bucket_sort(+row
// offsets) -> xcast -> gather.

#define DIM 128
#define RPB 128              // rows per bucket (power of 2)
#define ACHUNK 4096          // edges per bin block
#define BCAP 4096            // bucket sort LDS capacity (entries)
#define NBMAX 1024           // max buckets (N <= 131072)

__device__ __forceinline__ float sigmoidf_(float a) {
    return 1.0f / (1.0f + __expf(-a));
}
__device__ __forceinline__ unsigned f2bf(float f) {   // fp32 -> bf16 (RNE)
    unsigned u = __float_as_uint(f);
    return (u + 0x7FFFu + ((u >> 16) & 1u)) >> 16;
}

// x (fp32) -> xb (bf16), 4 elements per thread
__global__ __launch_bounds__(256)
void xcast_kernel(const float* __restrict__ x, unsigned short* __restrict__ xb,
                  int n4) {
    int i = blockIdx.x * blockDim.x + threadIdx.x;
    if (i >= n4) return;
    float4 v = reinterpret_cast<const float4*>(x)[i];
    uint2 o;
    o.x = f2bf(v.x) | (f2bf(v.y) << 16);
    o.y = f2bf(v.z) | (f2bf(v.w) << 16);
    reinterpret_cast<uint2*>(xb)[i] = o;
}

// per-bucket histogram, LDS-staged, int4-vectorized
__global__ __launch_bounds__(256)
void bucket_hist_kernel(const int* __restrict__ row, int* __restrict__ bhist,
                        int n_edges, int nb) {
    __shared__ int h[NBMAX];
    int t = threadIdx.x;
    for (int i = t; i < nb; i += 256) h[i] = 0;
    __syncthreads();
    int n4 = n_edges >> 2;
    for (int i = blockIdx.x * blockDim.x + t; i < n4;
         i += gridDim.x * blockDim.x) {
        int4 r = reinterpret_cast<const int4*>(row)[i];
        atomicAdd(&h[r.x >> 7], 1);
        atomicAdd(&h[r.y >> 7], 1);
        atomicAdd(&h[r.z >> 7], 1);
        atomicAdd(&h[r.w >> 7], 1);
    }
    if (blockIdx.x == 0 && t == 0) {
        for (int i = n4 << 2; i < n_edges; ++i)
            atomicAdd(&bhist[row[i] >> 7], 1);
    }
    __syncthreads();
    for (int i = t; i < nb; i += 256)
        if (h[i]) atomicAdd(&bhist[i], h[i]);
}

// single-block exclusive scan of bhist[0..nb) -> boffs[0..nb], bcur copy
__global__ __launch_bounds__(1024)
void bucket_scan_kernel(const int* __restrict__ bhist, int* __restrict__ boffs,
                        int* __restrict__ bcur, int nb) {
    __shared__ int ts[1024];
    int t = threadIdx.x;
    ts[t] = (t < nb) ? bhist[t] : 0;
    __syncthreads();
    for (int off = 1; off < 1024; off <<= 1) {
        int u = (t >= off) ? ts[t - off] : 0;
        __syncthreads();
        ts[t] += u;
        __syncthreads();
    }
    if (t < nb) {
        int e = (t == 0) ? 0 : ts[t - 1];
        boffs[t] = e;
        bcur[t] = e;
    }
    if (t == nb - 1) boffs[nb] = ts[t];
}

// bin edges into RPB-row buckets, LDS-staged so global writes are runs of
// consecutive slots. epackA entry: ((localrow<<17)|col, valbits)
__global__ __launch_bounds__(256)
void bin_kernel(const int* __restrict__ row, const int* __restrict__ col,
                const float* __restrict__ vals, int* __restrict__ bcursor,
                int2* __restrict__ epackA, int n_edges, int nb) {
    __shared__ int hist[NBMAX];
    __shared__ int lbase[NBMAX];
    __shared__ int gbase[NBMAX];
    __shared__ int lcur[NBMAX];
    __shared__ int ts[256];
    __shared__ int2 stage[ACHUNK];
    __shared__ int gpos[ACHUNK];
    int t = threadIdx.x;
    int base = blockIdx.x * ACHUNK;
    int m = n_edges - base;
    if (m > ACHUNK) m = ACHUNK;
    for (int i = t; i < nb; i += 256) hist[i] = 0;
    __syncthreads();
    for (int i = t; i < m; i += 256)
        atomicAdd(&hist[row[base + i] >> 7], 1);
    __syncthreads();
    int tb = t * 4;
    int h0 = (tb + 0 < nb) ? hist[tb + 0] : 0;
    int h1 = (tb + 1 < nb) ? hist[tb + 1] : 0;
    int h2 = (tb + 2 < nb) ? hist[tb + 2] : 0;
    int h3 = (tb + 3 < nb) ? hist[tb + 3] : 0;
    int s0 = h0, s1 = s0 + h1, s2 = s1 + h2, s3 = s2 + h3;
    ts[t] = s3;
    __syncthreads();
    for (int off = 1; off < 256; off <<= 1) {
        int u = (t >= off) ? ts[t - off] : 0;
        __syncthreads();
        ts[t] += u;
        __syncthreads();
    }
    int ex = (t == 0) ? 0 : ts[t - 1];
    if (tb + 0 < nb) lbase[tb + 0] = ex;
    if (tb + 1 < nb) lbase[tb + 1] = ex + s0;
    if (tb + 2 < nb) lbase[tb + 2] = ex + s1;
    if (tb + 3 < nb) lbase[tb + 3] = ex + s2;
    __syncthreads();
    for (int i = t; i < nb; i += 256) {
        gbase[i] = atomicAdd(&bcursor[i], hist[i]);
        lcur[i] = 0;
    }
    __syncthreads();
    for (int i = t; i < m; i += 256) {
        int r = row[base + i];
        int c = col[base + i];
        float v = vals[base + i];
        int bk = r >> 7;
        int lp = atomicAdd(&lcur[bk], 1);
        int sp = lbase[bk] + lp;
        stage[sp] = make_int2(((r & (RPB - 1)) << 17) | c, __float_as_int(v));
        gpos[sp] = gbase[bk] + lp;
    }
    __syncthreads();
    for (int i = t; i < m; i += 256)
        epackA[gpos[i]] = stage[i];
}

// one block per bucket, IN-PLACE sort to row order AND emit per-row offsets:
// local 128-row hist from the slice, local scan, offsets[r]=begin+excl,
// LDS scatter, coalesced write-back. Overflow path via global scratch.
__global__ __launch_bounds__(256)
void bucket_sort_kernel(const int* __restrict__ boffs,
                        int2* __restrict__ epackA,
                        int2* __restrict__ scratch,
                        int* __restrict__ offsets,
                        int n_nodes, int n_edges) {
    __shared__ int2 ein[BCAP];
    __shared__ int2 eout[BCAP];
    __shared__ int lrh[RPB];
    __shared__ int rowcur[RPB];
    int b = blockIdx.x;
    int t = threadIdx.x;
    int r0 = b * RPB;
    int begin = boffs[b];
    int end = boffs[b + 1];
    int n = end - begin;
    if (t < RPB) lrh[t] = 0;
    __syncthreads();
    if (n <= BCAP) {
        for (int i = t; i < n; i += 256) {
            int2 e = epackA[begin + i];
            ein[i] = e;
            atomicAdd(&lrh[e.x >> 17], 1);
        }
        __syncthreads();
        if (t < RPB) rowcur[t] = lrh[t];
        __syncthreads();
        for (int off = 1; off < RPB; off <<= 1) {
            int u = (t < RPB && t >= off) ? rowcur[t - off] : 0;
            __syncthreads();
            if (t < RPB) rowcur[t] += u;
            __syncthreads();
        }
        if (t < RPB) {
            int excl = rowcur[t] - lrh[t];      // inclusive -> exclusive
            rowcur[t] = excl;
            int r = r0 + t;
            if (r < n_nodes) offsets[r] = begin + excl;
        }
        __syncthreads();
        for (int i = t; i < n; i += 256) {
            int2 e = ein[i];
            int pos = atomicAdd(&rowcur[e.x >> 17], 1);
            eout[pos] = make_int2(e.x & 0x1FFFF, e.y);
        }
        __syncthreads();
        for (int i = t; i < n; i += 256) epackA[begin + i] = eout[i];
    } else {
        // fallback (can't occur for ~2048-edge buckets): global two-pass
        for (int i = t; i < n; i += 256)
            atomicAdd(&lrh[epackA[begin + i].x >> 17], 1);
        __syncthreads();
        if (t < RPB) rowcur[t] = lrh[t];
        __syncthreads();
        for (int off = 1; off < RPB; off <<= 1) {
            int u = (t < RPB && t >= off) ? rowcur[t - off] : 0;
            __syncthreads();
            if (t < RPB) rowcur[t] += u;
            __syncthreads();
        }
        if (t < RPB) {
            int excl = rowcur[t] - lrh[t];
            rowcur[t] = excl;
            int r = r0 + t;
            if (r < n_nodes) offsets[r] = begin + excl;
        }
        __syncthreads();
        for (int i = t; i < n; i += 256) {
            int2 e = epackA[begin + i];
            int pos = atomicAdd(&rowcur[e.x >> 17], 1);
            scratch[begin + pos] = make_int2(e.x & 0x1FFFF, e.y);
        }
        __syncthreads();
        for (int i = t; i < n; i += 256) epackA[begin + i] = scratch[begin + i];
    }
}

// wave per row; lane owns 2 columns. Edge metadata loaded lane-parallel,
// broadcast via __shfl; bf16 source rows (1 dword/lane), 8-deep pipelined.
__global__ __launch_bounds__(256)
void csr_gather_bf16_kernel(const unsigned short* __restrict__ xb,
                            const float* __restrict__ x,
                            const float* __restrict__ x0,
                            const float* __restrict__ alpha,
                            const int* __restrict__ offsets,
                            const int2* __restrict__ epack,
                            float* __restrict__ out, int n_nodes, int n_edges) {
    int gid = blockIdx.x * blockDim.x + threadIdx.x;
    int r = gid >> 6;
    int lane = gid & 63;
    if (r >= n_nodes) return;
    float s = 0.5f * sigmoidf_(alpha[r]);
    const unsigned* xbp = reinterpret_cast<const unsigned*>(xb);  // row stride 64
    int rb = r * 64;
    float2 xv = reinterpret_cast<const float2*>(x)[rb + lane];
    float2 acc = reinterpret_cast<const float2*>(x0)[rb + lane];
    acc.x -= s * xv.x;
    acc.y -= s * xv.y;
    int beg = offsets[r];
    int stop = (r + 1 < n_nodes) ? offsets[r + 1] : n_edges;
    for (int chunk = beg; chunk < stop; chunk += 64) {
        int m = stop - chunk;
        if (m > 64) m = 64;
        int2 e = (lane < m) ? epack[chunk + lane] : make_int2(0, 0);
        int k = 0;
        for (; k + 8 <= m; k += 8) {
            unsigned d[8]; float w[8];
#pragma unroll
            for (int j = 0; j < 8; ++j) {
                int c = __shfl(e.x, k + j);
                w[j] = s * __int_as_float(__shfl(e.y, k + j));
                d[j] = xbp[(size_t)c * 64 + lane];
            }
#pragma unroll
            for (int j = 0; j < 8; ++j) {
                acc.x += w[j] * __uint_as_float((d[j] & 0xFFFFu) << 16);
                acc.y += w[j] * __uint_as_float(d[j] & 0xFFFF0000u);
            }
        }
        for (; k < m; ++k) {
            int c = __shfl(e.x, k);
            float w = s * __int_as_float(__shfl(e.y, k));
            unsigned d = xbp[(size_t)c * 64 + lane];
            acc.x += w * __uint_as_float((d & 0xFFFFu) << 16);
            acc.y += w * __uint_as_float(d & 0xFFFF0000u);
        }
    }
    reinterpret_cast<float2*>(out)[rb + lane] = acc;
}

// fp32 fallback gather (4-wide)
__global__ __launch_bounds__(256)
void csr_gather_f32_kernel(const float* __restrict__ x,
                           const float* __restrict__ x0,
                           const float* __restrict__ alpha,
                           const int* __restrict__ offsets,
                           const int2* __restrict__ epack,
                           float* __restrict__ out, int n_nodes, int n_edges) {
    int gid = blockIdx.x * blockDim.x + threadIdx.x;
    int r = gid >> 6;
    int lane = gid & 63;
    if (r >= n_nodes) return;
    float s = 0.5f * sigmoidf_(alpha[r]);
    const float2* xp = reinterpret_cast<const float2*>(x);
    int rb = r * 64;
    float2 xv = xp[rb + lane];
    float2 acc = reinterpret_cast<const float2*>(x0)[rb + lane];
    acc.x -= s * xv.x;
    acc.y -= s * xv.y;
    int beg = offsets[r];
    int stop = (r + 1 < n_nodes) ? offsets[r + 1] : n_edges;
    for (int chunk = beg; chunk < stop; chunk += 64) {
        int m = stop - chunk;
        if (m > 64) m = 64;
        int2 e = (lane < m) ? epack[chunk + lane] : make_int2(0, 0);
        int k = 0;
        for (; k + 4 <= m; k += 4) {
            int c0 = __shfl(e.x, k + 0);
            int c1 = __shfl(e.x, k + 1);
            int c2 = __shfl(e.x, k + 2);
            int c3 = __shfl(e.x, k + 3);
            float w0 = s * __int_as_float(__shfl(e.y, k + 0));
            float w1 = s * __int_as_float(__shfl(e.y, k + 1));
            float w2 = s * __int_as_float(__shfl(e.y, k + 2));
            float w3 = s * __int_as_float(__shfl(e.y, k + 3));
            float2 v0 = xp[(size_t)c0 * 64 + lane];
            float2 v1 = xp[(size_t)c1 * 64 + lane];
            float2 v2 = xp[(size_t)c2 * 64 + lane];
            float2 v3 = xp[(size_t)c3 * 64 + lane];
            acc.x += w0 * v0.x; acc.y += w0 * v0.y;
            acc.x += w1 * v1.x; acc.y += w1 * v1.y;
            acc.x += w2 * v2.x; acc.y += w2 * v2.y;
            acc.x += w3 * v3.x; acc.y += w3 * v3.y;
        }
        for (; k < m; ++k) {
            int c = __shfl(e.x, k);
            float w = s * __int_as_float(__shfl(e.y, k));
            float2 v = xp[(size_t)c * 64 + lane];
            acc.x += w * v.x;
            acc.y += w * v.y;
        }
    }
    reinterpret_cast<float2*>(out)[rb + lane] = acc;
}

extern "C" void kernel_launch(void* const* d_in, const int* in_sizes, int n_in,
                              void* d_out, int out_size, void* d_ws, size_t ws_size,
                              hipStream_t stream) {
    // inputs: 0=t(unused), 1=x[N,D], 2=x0[N,D], 3=alpha[N], 4=vals[E],
    //         5=row[E](i32), 6=col[E](i32)
    const float* x     = (const float*)d_in[1];
    const float* x0    = (const float*)d_in[2];
    const float* alpha = (const float*)d_in[3];
    const float* vals  = (const float*)d_in[4];
    const int*   row   = (const int*)d_in[5];
    const int*   col   = (const int*)d_in[6];
    float* out = (float*)d_out;

    int n_nodes = in_sizes[3];
    int n_edges = in_sizes[4];
    int nb = (n_nodes + RPB - 1) / RPB;            // 782 buckets

    // workspace layout
    size_t npad = (size_t)((n_nodes + 3) & ~3);
    int*  bhist   = (int*)d_ws;                    // NBMAX
    int*  boffs   = bhist + NBMAX;                 // NBMAX+16
    int*  bcur    = boffs + NBMAX + 16;            // NBMAX
    int*  offsets = bcur + NBMAX;                  // npad
    char* p       = (char*)(offsets + npad);
    size_t base_bytes = (size_t)(p - (char*)d_ws);
    size_t xb_bytes = (size_t)n_nodes * DIM * sizeof(unsigned short);
    size_t ep_bytes = (size_t)((n_edges + 3) & ~3) * sizeof(int2);
    int use_bf16 = (ws_size >= base_bytes + xb_bytes + ep_bytes + 256) ? 1 : 0;

    unsigned short* xxb;
    int2* epackA;
    int2* scratch;
    if (use_bf16) {
        xxb = (unsigned short*)p;
        epackA = (int2*)(p + ((xb_bytes + 255) & ~(size_t)255));
        scratch = (int2*)p;      // xb region; only used pre-xcast (overflow)
    } else {
        xxb = nullptr;
        epackA = (int2*)p;
        scratch = epackA + ((n_edges + 3) & ~3);
    }

    hipMemsetAsync(bhist, 0, NBMAX * sizeof(int), stream);

    bucket_hist_kernel<<<256, 256, 0, stream>>>(row, bhist, n_edges, nb);
    bucket_scan_kernel<<<1, 1024, 0, stream>>>(bhist, boffs, bcur, nb);
    {
        int grid = (n_edges + ACHUNK - 1) / ACHUNK;
        bin_kernel<<<grid, 256, 0, stream>>>(row, col, vals, bcur, epackA,
                                             n_edges, nb);
    }
    bucket_sort_kernel<<<nb, 256, 0, stream>>>(boffs, epackA, scratch,
                                               offsets, n_nodes, n_edges);
    {
        long long total = (long long)n_nodes * 64;
        int block = 256;
        int grid = (int)((total + block - 1) / block);
        if (use_bf16) {
            int n4 = (n_nodes * DIM) >> 2;
            xcast_kernel<<<(n4 + 255) / 256, 256, 0, stream>>>(x, xxb, n4);
            csr_gather_bf16_kernel<<<grid, block, 0, stream>>>(
                xxb, x, x0, alpha, offsets, epackA, out, n_nodes, n_edges);
        } else {
            csr_gather_f32_kernel<<<grid, block, 0, stream>>>(
                x, x0, alpha, offsets, epackA, out, n_nodes, n_edges);
        }
    }
}

// Round 9
// 139.424 us; speedup vs baseline: 10.3281x; 1.1802x over previous
//
#include <hip/hip_runtime.h>

// out = sigmoid(alpha)[:,None] * 0.5 * (ax - x) + x0
// ax = segment_sum(adj_values[:,None] * x[adj_col], adj_row)
//
// R9: (1) xb moved to ws offset 0 -- R8 put it at 192 mod 256, making every
// gathered 256B row straddle an extra 128B memory granule (FETCH 239->320MB,
// gather 82->97.6us). (2) bucket_sort fused INTO the gather: block per bucket
// sorts its epackA slice in LDS (row hist+scan+scatter, offsets stay in LDS),
// then 8 waves x 16 rows gather with edge meta from LDS broadcast. Kills the
// bucket_sort kernel (25.6MB traffic) and the global offsets array.

#define DIM 128
#define RPB 128              // rows per bucket (power of 2)
#define ACHUNK 4096          // edges per bin block
#define BCAP 4096            // fused-kernel LDS sort capacity (entries)
#define NBMAX 1024           // max buckets (N <= 131072)

__device__ __forceinline__ float sigmoidf_(float a) {
    return 1.0f / (1.0f + __expf(-a));
}
__device__ __forceinline__ unsigned f2bf(float f) {   // fp32 -> bf16 (RNE)
    unsigned u = __float_as_uint(f);
    return (u + 0x7FFFu + ((u >> 16) & 1u)) >> 16;
}

// x (fp32) -> xb (bf16), 4 elements per thread
__global__ __launch_bounds__(256)
void xcast_kernel(const float* __restrict__ x, unsigned short* __restrict__ xb,
                  int n4) {
    int i = blockIdx.x * blockDim.x + threadIdx.x;
    if (i >= n4) return;
    float4 v = reinterpret_cast<const float4*>(x)[i];
    uint2 o;
    o.x = f2bf(v.x) | (f2bf(v.y) << 16);
    o.y = f2bf(v.z) | (f2bf(v.w) << 16);
    reinterpret_cast<uint2*>(xb)[i] = o;
}

// per-bucket histogram, LDS-staged, int4-vectorized
__global__ __launch_bounds__(256)
void bucket_hist_kernel(const int* __restrict__ row, int* __restrict__ bhist,
                        int n_edges, int nb) {
    __shared__ int h[NBMAX];
    int t = threadIdx.x;
    for (int i = t; i < nb; i += 256) h[i] = 0;
    __syncthreads();
    int n4 = n_edges >> 2;
    for (int i = blockIdx.x * blockDim.x + t; i < n4;
         i += gridDim.x * blockDim.x) {
        int4 r = reinterpret_cast<const int4*>(row)[i];
        atomicAdd(&h[r.x >> 7], 1);
        atomicAdd(&h[r.y >> 7], 1);
        atomicAdd(&h[r.z >> 7], 1);
        atomicAdd(&h[r.w >> 7], 1);
    }
    if (blockIdx.x == 0 && t == 0) {
        for (int i = n4 << 2; i < n_edges; ++i)
            atomicAdd(&bhist[row[i] >> 7], 1);
    }
    __syncthreads();
    for (int i = t; i < nb; i += 256)
        if (h[i]) atomicAdd(&bhist[i], h[i]);
}

// single-block exclusive scan of bhist[0..nb) -> boffs[0..nb], bcur copy
__global__ __launch_bounds__(1024)
void bucket_scan_kernel(const int* __restrict__ bhist, int* __restrict__ boffs,
                        int* __restrict__ bcur, int nb) {
    __shared__ int ts[1024];
    int t = threadIdx.x;
    ts[t] = (t < nb) ? bhist[t] : 0;
    __syncthreads();
    for (int off = 1; off < 1024; off <<= 1) {
        int u = (t >= off) ? ts[t - off] : 0;
        __syncthreads();
        ts[t] += u;
        __syncthreads();
    }
    if (t < nb) {
        int e = (t == 0) ? 0 : ts[t - 1];
        boffs[t] = e;
        bcur[t] = e;
    }
    if (t == nb - 1) boffs[nb] = ts[t];
}

// bin edges into RPB-row buckets, LDS-staged so global writes are runs of
// consecutive slots. epackA entry: ((localrow<<17)|col, valbits)
__global__ __launch_bounds__(256)
void bin_kernel(const int* __restrict__ row, const int* __restrict__ col,
                const float* __restrict__ vals, int* __restrict__ bcursor,
                int2* __restrict__ epackA, int n_edges, int nb) {
    __shared__ int hist[NBMAX];
    __shared__ int lbase[NBMAX];
    __shared__ int gbase[NBMAX];
    __shared__ int lcur[NBMAX];
    __shared__ int ts[256];
    __shared__ int2 stage[ACHUNK];
    __shared__ int gpos[ACHUNK];
    int t = threadIdx.x;
    int base = blockIdx.x * ACHUNK;
    int m = n_edges - base;
    if (m > ACHUNK) m = ACHUNK;
    for (int i = t; i < nb; i += 256) hist[i] = 0;
    __syncthreads();
    for (int i = t; i < m; i += 256)
        atomicAdd(&hist[row[base + i] >> 7], 1);
    __syncthreads();
    int tb = t * 4;
    int h0 = (tb + 0 < nb) ? hist[tb + 0] : 0;
    int h1 = (tb + 1 < nb) ? hist[tb + 1] : 0;
    int h2 = (tb + 2 < nb) ? hist[tb + 2] : 0;
    int h3 = (tb + 3 < nb) ? hist[tb + 3] : 0;
    int s0 = h0, s1 = s0 + h1, s2 = s1 + h2, s3 = s2 + h3;
    ts[t] = s3;
    __syncthreads();
    for (int off = 1; off < 256; off <<= 1) {
        int u = (t >= off) ? ts[t - off] : 0;
        __syncthreads();
        ts[t] += u;
        __syncthreads();
    }
    int ex = (t == 0) ? 0 : ts[t - 1];
    if (tb + 0 < nb) lbase[tb + 0] = ex;
    if (tb + 1 < nb) lbase[tb + 1] = ex + s0;
    if (tb + 2 < nb) lbase[tb + 2] = ex + s1;
    if (tb + 3 < nb) lbase[tb + 3] = ex + s2;
    __syncthreads();
    for (int i = t; i < nb; i += 256) {
        gbase[i] = atomicAdd(&bcursor[i], hist[i]);
        lcur[i] = 0;
    }
    __syncthreads();
    for (int i = t; i < m; i += 256) {
        int r = row[base + i];
        int c = col[base + i];
        float v = vals[base + i];
        int bk = r >> 7;
        int lp = atomicAdd(&lcur[bk], 1);
        int sp = lbase[bk] + lp;
        stage[sp] = make_int2(((r & (RPB - 1)) << 17) | c, __float_as_int(v));
        gpos[sp] = gbase[bk] + lp;
    }
    __syncthreads();
    for (int i = t; i < m; i += 256)
        epackA[gpos[i]] = stage[i];
}

// Fused sort+gather: one 512-thread block per bucket.
//  1) hist localrow over the bucket's epackA slice (global stream)
//  2) 128-wide LDS scan -> row starts (stay in LDS)
//  3) scatter sorted (col,val) into eout[] in LDS
//  4) 8 waves x 16 rows: acc = x0 - s*x; loop edges (meta via LDS broadcast,
//     8-deep pipelined bf16/f32 row gathers); store out row.
template <int USE_BF16>
__global__ __launch_bounds__(512)
void fused_sort_gather_kernel(const unsigned short* __restrict__ xb,
                              const float* __restrict__ x,
                              const float* __restrict__ x0,
                              const float* __restrict__ alpha,
                              const int* __restrict__ boffs,
                              const int2* __restrict__ epackA,
                              float* __restrict__ out, int n_nodes) {
    __shared__ int2 eout[BCAP];
    __shared__ int rowstart[RPB];
    __shared__ int rowcur[RPB];
    __shared__ float sval[RPB];
    int b = blockIdx.x, t = threadIdx.x;
    int r0 = b * RPB;
    int begin = boffs[b], end = boffs[b + 1];
    int n = end - begin;
    if (t < RPB) {
        int r = r0 + t;
        sval[t] = (r < n_nodes) ? 0.5f * sigmoidf_(alpha[r]) : 0.f;
        rowstart[t] = 0;
    }
    __syncthreads();
    int wave = t >> 6, lane = t & 63;
    const unsigned* xbp = reinterpret_cast<const unsigned*>(xb);
    const float2* xp = reinterpret_cast<const float2*>(x);
    if (n <= BCAP) {
        // pass 1: histogram local rows
        for (int i = t; i < n; i += 512)
            atomicAdd(&rowstart[epackA[begin + i].x >> 17], 1);
        __syncthreads();
        if (t < RPB) rowcur[t] = rowstart[t];
        __syncthreads();
        for (int off = 1; off < RPB; off <<= 1) {
            int u = (t < RPB && t >= off) ? rowcur[t - off] : 0;
            __syncthreads();
            if (t < RPB) rowcur[t] += u;
            __syncthreads();
        }
        if (t < RPB) {
            int excl = rowcur[t] - rowstart[t];   // inclusive -> exclusive
            rowstart[t] = excl;
            rowcur[t] = excl;
        }
        __syncthreads();
        // pass 2: scatter sorted meta into LDS
        for (int i = t; i < n; i += 512) {
            int2 e = epackA[begin + i];
            int pos = atomicAdd(&rowcur[e.x >> 17], 1);
            eout[pos] = make_int2(e.x & 0x1FFFF, e.y);
        }
        __syncthreads();
        // gather: wave handles rows [wave*16, wave*16+16)
        for (int q = 0; q < 16; ++q) {
            int lr = wave * 16 + q;
            int r = r0 + lr;
            if (r >= n_nodes) break;
            float s = sval[lr];
            int rb = r * 64;
            float2 xv = xp[rb + lane];
            float2 acc = reinterpret_cast<const float2*>(x0)[rb + lane];
            acc.x -= s * xv.x;
            acc.y -= s * xv.y;
            int k = rowstart[lr];
            int stop = (lr + 1 < RPB) ? rowstart[lr + 1] : n;
            for (; k + 8 <= stop; k += 8) {
                float w[8];
                if (USE_BF16) {
                    unsigned d[8];
#pragma unroll
                    for (int j = 0; j < 8; ++j) {
                        int2 e = eout[k + j];
                        w[j] = s * __int_as_float(e.y);
                        d[j] = xbp[(size_t)e.x * 64 + lane];
                    }
#pragma unroll
                    for (int j = 0; j < 8; ++j) {
                        acc.x += w[j] * __uint_as_float((d[j] & 0xFFFFu) << 16);
                        acc.y += w[j] * __uint_as_float(d[j] & 0xFFFF0000u);
                    }
                } else {
                    float2 v[8];
#pragma unroll
                    for (int j = 0; j < 8; ++j) {
                        int2 e = eout[k + j];
                        w[j] = s * __int_as_float(e.y);
                        v[j] = xp[(size_t)e.x * 64 + lane];
                    }
#pragma unroll
                    for (int j = 0; j < 8; ++j) {
                        acc.x += w[j] * v[j].x;
                        acc.y += w[j] * v[j].y;
                    }
                }
            }
            for (; k < stop; ++k) {
                int2 e = eout[k];
                float w = s * __int_as_float(e.y);
                if (USE_BF16) {
                    unsigned d = xbp[(size_t)e.x * 64 + lane];
                    acc.x += w * __uint_as_float((d & 0xFFFFu) << 16);
                    acc.y += w * __uint_as_float(d & 0xFFFF0000u);
                } else {
                    float2 v = xp[(size_t)e.x * 64 + lane];
                    acc.x += w * v.x;
                    acc.y += w * v.y;
                }
            }
            reinterpret_cast<float2*>(out)[rb + lane] = acc;
        }
    } else {
        // correctness-only fallback (unreachable for ~2k-edge buckets):
        // each wave rescans the whole slice for each of its rows.
        for (int q = 0; q < 16; ++q) {
            int lr = wave * 16 + q;
            int r = r0 + lr;
            if (r >= n_nodes) break;
            float s = sval[lr];
            int rb = r * 64;
            float2 xv = xp[rb + lane];
            float2 acc = reinterpret_cast<const float2*>(x0)[rb + lane];
            acc.x -= s * xv.x;
            acc.y -= s * xv.y;
            for (int i = 0; i < n; ++i) {
                int2 e = epackA[begin + i];
                if ((e.x >> 17) == lr) {
                    float w = s * __int_as_float(e.y);
                    if (USE_BF16) {
                        unsigned d = xbp[(size_t)(e.x & 0x1FFFF) * 64 + lane];
                        acc.x += w * __uint_as_float((d & 0xFFFFu) << 16);
                        acc.y += w * __uint_as_float(d & 0xFFFF0000u);
                    } else {
                        float2 v = xp[(size_t)(e.x & 0x1FFFF) * 64 + lane];
                        acc.x += w * v.x;
                        acc.y += w * v.y;
                    }
                }
            }
            reinterpret_cast<float2*>(out)[rb + lane] = acc;
        }
    }
}

extern "C" void kernel_launch(void* const* d_in, const int* in_sizes, int n_in,
                              void* d_out, int out_size, void* d_ws, size_t ws_size,
                              hipStream_t stream) {
    // inputs: 0=t(unused), 1=x[N,D], 2=x0[N,D], 3=alpha[N], 4=vals[E],
    //         5=row[E](i32), 6=col[E](i32)
    const float* x     = (const float*)d_in[1];
    const float* x0    = (const float*)d_in[2];
    const float* alpha = (const float*)d_in[3];
    const float* vals  = (const float*)d_in[4];
    const int*   row   = (const int*)d_in[5];
    const int*   col   = (const int*)d_in[6];
    float* out = (float*)d_out;

    int n_nodes = in_sizes[3];
    int n_edges = in_sizes[4];
    int nb = (n_nodes + RPB - 1) / RPB;            // 782 buckets

    // workspace layout: xb FIRST (256B-aligned -> minimal gather granules)
    size_t xb_bytes = (size_t)n_nodes * DIM * sizeof(unsigned short);
    size_t ep_bytes = (size_t)((n_edges + 3) & ~3) * sizeof(int2);
    size_t meta_bytes = (size_t)(NBMAX + NBMAX + 16 + NBMAX) * sizeof(int);
    int use_bf16 = (ws_size >= xb_bytes + ep_bytes + meta_bytes + 512) ? 1 : 0;

    unsigned short* xxb;
    int2* epackA;
    int* bhist;
    if (use_bf16) {
        xxb    = (unsigned short*)d_ws;
        epackA = (int2*)((char*)d_ws + xb_bytes);
        bhist  = (int*)((char*)epackA + ep_bytes);
    } else {
        xxb    = nullptr;
        epackA = (int2*)d_ws;
        bhist  = (int*)((char*)epackA + ep_bytes);
    }
    int* boffs = bhist + NBMAX;                    // NBMAX+16
    int* bcur  = boffs + NBMAX + 16;               // NBMAX

    hipMemsetAsync(bhist, 0, NBMAX * sizeof(int), stream);

    if (use_bf16) {
        int n4 = (n_nodes * DIM) >> 2;
        xcast_kernel<<<(n4 + 255) / 256, 256, 0, stream>>>(x, xxb, n4);
    }
    bucket_hist_kernel<<<256, 256, 0, stream>>>(row, bhist, n_edges, nb);
    bucket_scan_kernel<<<1, 1024, 0, stream>>>(bhist, boffs, bcur, nb);
    {
        int grid = (n_edges + ACHUNK - 1) / ACHUNK;
        bin_kernel<<<grid, 256, 0, stream>>>(row, col, vals, bcur, epackA,
                                             n_edges, nb);
    }
    if (use_bf16) {
        fused_sort_gather_kernel<1><<<nb, 512, 0, stream>>>(
            xxb, x, x0, alpha, boffs, epackA, out, n_nodes);
    } else {
        fused_sort_gather_kernel<0><<<nb, 512, 0, stream>>>(
            xxb, x, x0, alpha, boffs, epackA, out, n_nodes);
    }
}

// Round 10
// 134.565 us; speedup vs baseline: 10.7011x; 1.0361x over previous
//
#include <hip/hip_runtime.h>

// out = sigmoid(alpha)[:,None] * 0.5 * (ax - x) + x0
// ax = segment_sum(adj_values[:,None] * x[adj_col], adj_row)
//
// R10: R9's fused kernel was grid-limited (782 blocks / 256 CUs = 3.05/CU vs
// 4-block thread cap; Occupancy 55%). RPB 128->64 doubles the grid (1563
// blocks) -> full 2048 thr/CU, shorter sort prologue. Epilogue now reads the
// bf16 xb for the -s*x term (saves 51MB fp32 stream). xcast and bucket_hist
// merged into one kernel (hist hides under xcast BW). bin widened to
// NBMAX=2048 buckets (8-per-thread scan, ushort bucket-id instead of gpos).

#define DIM 128
#define RPB 64               // rows per bucket (power of 2); shift = 6
#define RSHIFT 6
#define ACHUNK 4096          // edges per bin block
#define BCAP 2048            // fused-kernel LDS sort capacity (entries)
#define NBMAX 2048           // max buckets (N <= 131072)
#define HISTB 128            // hist blocks appended to xcast grid

__device__ __forceinline__ float sigmoidf_(float a) {
    return 1.0f / (1.0f + __expf(-a));
}
__device__ __forceinline__ unsigned f2bf(float f) {   // fp32 -> bf16 (RNE)
    unsigned u = __float_as_uint(f);
    return (u + 0x7FFFu + ((u >> 16) & 1u)) >> 16;
}

// combined: blocks [0,xg) cast x->bf16; blocks [xg, xg+HISTB) histogram rows
// into NBMAX buckets (LDS-staged).
__global__ __launch_bounds__(256)
void xcast_hist_kernel(const float* __restrict__ x,
                       unsigned short* __restrict__ xb, int n4,
                       const int* __restrict__ row, int* __restrict__ bhist,
                       int n_edges, int nb, int xg) {
    __shared__ int h[NBMAX];
    if ((int)blockIdx.x < xg) {
        int i = blockIdx.x * 256 + threadIdx.x;
        if (i >= n4) return;
        float4 v = reinterpret_cast<const float4*>(x)[i];
        uint2 o;
        o.x = f2bf(v.x) | (f2bf(v.y) << 16);
        o.y = f2bf(v.z) | (f2bf(v.w) << 16);
        reinterpret_cast<uint2*>(xb)[i] = o;
        return;
    }
    int t = threadIdx.x;
    int bid = blockIdx.x - xg;
    for (int i = t; i < NBMAX; i += 256) h[i] = 0;
    __syncthreads();
    int e4 = n_edges >> 2;
    for (int i = bid * 256 + t; i < e4; i += HISTB * 256) {
        int4 r = reinterpret_cast<const int4*>(row)[i];
        atomicAdd(&h[r.x >> RSHIFT], 1);
        atomicAdd(&h[r.y >> RSHIFT], 1);
        atomicAdd(&h[r.z >> RSHIFT], 1);
        atomicAdd(&h[r.w >> RSHIFT], 1);
    }
    if (bid == 0 && t == 0) {
        for (int i = e4 << 2; i < n_edges; ++i)
            atomicAdd(&bhist[row[i] >> RSHIFT], 1);
    }
    __syncthreads();
    for (int i = t; i < NBMAX; i += 256)
        if (h[i]) atomicAdd(&bhist[i], h[i]);
}

// single-block exclusive scan of bhist[0..nb) -> boffs[0..nb], bcur copy
// (nb <= 2048: 2 elements per thread)
__global__ __launch_bounds__(1024)
void bucket_scan_kernel(const int* __restrict__ bhist, int* __restrict__ boffs,
                        int* __restrict__ bcur, int nb) {
    __shared__ int ts[1024];
    int t = threadIdx.x;
    int i0 = 2 * t, i1 = 2 * t + 1;
    int v0 = (i0 < nb) ? bhist[i0] : 0;
    int v1 = (i1 < nb) ? bhist[i1] : 0;
    ts[t] = v0 + v1;
    __syncthreads();
    for (int off = 1; off < 1024; off <<= 1) {
        int u = (t >= off) ? ts[t - off] : 0;
        __syncthreads();
        ts[t] += u;
        __syncthreads();
    }
    int ex = (t == 0) ? 0 : ts[t - 1];
    if (i0 < nb) { boffs[i0] = ex;      bcur[i0] = ex; }
    if (i1 < nb) { boffs[i1] = ex + v0; bcur[i1] = ex + v0; }
    if (t == 1023) boffs[nb] = ts[1023];
}

// bin edges into RPB-row buckets, LDS-staged so global writes are runs of
// consecutive slots. epackA entry: ((localrow<<17)|col, valbits)
__global__ __launch_bounds__(256)
void bin_kernel(const int* __restrict__ row, const int* __restrict__ col,
                const float* __restrict__ vals, int* __restrict__ bcursor,
                int2* __restrict__ epackA, int n_edges, int nb) {
    __shared__ int hist[NBMAX];
    __shared__ int lbase[NBMAX];
    __shared__ int gbase[NBMAX];
    __shared__ int lcur[NBMAX];
    __shared__ int ts[256];
    __shared__ int2 stage[ACHUNK];
    __shared__ unsigned short bkid[ACHUNK];
    int t = threadIdx.x;
    int base = blockIdx.x * ACHUNK;
    int m = n_edges - base;
    if (m > ACHUNK) m = ACHUNK;
    for (int i = t; i < NBMAX; i += 256) hist[i] = 0;
    __syncthreads();
    for (int i = t; i < m; i += 256)
        atomicAdd(&hist[row[base + i] >> RSHIFT], 1);
    __syncthreads();
    // 8-per-thread exclusive scan over NBMAX=2048
    int tb = t * 8;
    int hh[8];
    int run = 0;
#pragma unroll
    for (int j = 0; j < 8; ++j) { hh[j] = hist[tb + j]; run += hh[j]; }
    ts[t] = run;
    __syncthreads();
    for (int off = 1; off < 256; off <<= 1) {
        int u = (t >= off) ? ts[t - off] : 0;
        __syncthreads();
        ts[t] += u;
        __syncthreads();
    }
    int ex = (t == 0) ? 0 : ts[t - 1];
#pragma unroll
    for (int j = 0; j < 8; ++j) { lbase[tb + j] = ex; ex += hh[j]; }
    __syncthreads();
    for (int i = t; i < nb; i += 256) {
        gbase[i] = atomicAdd(&bcursor[i], hist[i]);
        lcur[i] = 0;
    }
    __syncthreads();
    for (int i = t; i < m; i += 256) {
        int r = row[base + i];
        int c = col[base + i];
        float v = vals[base + i];
        int bk = r >> RSHIFT;
        int lp = atomicAdd(&lcur[bk], 1);
        int sp = lbase[bk] + lp;
        stage[sp] = make_int2(((r & (RPB - 1)) << 17) | c, __float_as_int(v));
        bkid[sp] = (unsigned short)bk;
    }
    __syncthreads();
    for (int i = t; i < m; i += 256) {
        int bk = bkid[i];
        epackA[gbase[bk] + (i - lbase[bk])] = stage[i];
    }
}

// Fused sort+gather: one 512-thread block per 64-row bucket.
//  1) hist localrow over the bucket's epackA slice
//  2) 64-wide LDS scan -> row starts (stay in LDS)
//  3) scatter sorted (col,val) into eout[] in LDS
//  4) 8 waves x 8 rows: acc = x0 - s*x(bf16); loop edges (meta via LDS
//     broadcast, 8-deep pipelined row gathers); store out row.
template <int USE_BF16>
__global__ __launch_bounds__(512)
void fused_sort_gather_kernel(const unsigned short* __restrict__ xb,
                              const float* __restrict__ x,
                              const float* __restrict__ x0,
                              const float* __restrict__ alpha,
                              const int* __restrict__ boffs,
                              const int2* __restrict__ epackA,
                              float* __restrict__ out, int n_nodes) {
    __shared__ int2 eout[BCAP];
    __shared__ int rowstart[RPB];
    __shared__ int rowcur[RPB];
    __shared__ float sval[RPB];
    int b = blockIdx.x, t = threadIdx.x;
    int r0 = b * RPB;
    int begin = boffs[b], end = boffs[b + 1];
    int n = end - begin;
    if (t < RPB) {
        int r = r0 + t;
        sval[t] = (r < n_nodes) ? 0.5f * sigmoidf_(alpha[r]) : 0.f;
        rowstart[t] = 0;
    }
    __syncthreads();
    int wave = t >> 6, lane = t & 63;
    const unsigned* xbp = reinterpret_cast<const unsigned*>(xb);
    const float2* xp = reinterpret_cast<const float2*>(x);
    if (n <= BCAP) {
        for (int i = t; i < n; i += 512)
            atomicAdd(&rowstart[epackA[begin + i].x >> 17], 1);
        __syncthreads();
        if (t < RPB) rowcur[t] = rowstart[t];
        __syncthreads();
        for (int off = 1; off < RPB; off <<= 1) {
            int u = (t < RPB && t >= off) ? rowcur[t - off] : 0;
            __syncthreads();
            if (t < RPB) rowcur[t] += u;
            __syncthreads();
        }
        if (t < RPB) {
            int excl = rowcur[t] - rowstart[t];   // inclusive -> exclusive
            rowstart[t] = excl;
            rowcur[t] = excl;
        }
        __syncthreads();
        for (int i = t; i < n; i += 512) {
            int2 e = epackA[begin + i];
            int pos = atomicAdd(&rowcur[e.x >> 17], 1);
            eout[pos] = make_int2(e.x & 0x1FFFF, e.y);
        }
        __syncthreads();
        for (int q = 0; q < 8; ++q) {
            int lr = wave * 8 + q;
            int r = r0 + lr;
            if (r >= n_nodes) break;
            float s = sval[lr];
            int rb = r * 64;
            float2 acc = reinterpret_cast<const float2*>(x0)[rb + lane];
            if (USE_BF16) {
                unsigned dx = xbp[rb + lane];
                acc.x -= s * __uint_as_float((dx & 0xFFFFu) << 16);
                acc.y -= s * __uint_as_float(dx & 0xFFFF0000u);
            } else {
                float2 xv = xp[rb + lane];
                acc.x -= s * xv.x;
                acc.y -= s * xv.y;
            }
            int k = rowstart[lr];
            int stop = (lr + 1 < RPB) ? rowstart[lr + 1] : n;
            for (; k + 8 <= stop; k += 8) {
                float w[8];
                if (USE_BF16) {
                    unsigned d[8];
#pragma unroll
                    for (int j = 0; j < 8; ++j) {
                        int2 e = eout[k + j];
                        w[j] = s * __int_as_float(e.y);
                        d[j] = xbp[(size_t)e.x * 64 + lane];
                    }
#pragma unroll
                    for (int j = 0; j < 8; ++j) {
                        acc.x += w[j] * __uint_as_float((d[j] & 0xFFFFu) << 16);
                        acc.y += w[j] * __uint_as_float(d[j] & 0xFFFF0000u);
                    }
                } else {
                    float2 v[8];
#pragma unroll
                    for (int j = 0; j < 8; ++j) {
                        int2 e = eout[k + j];
                        w[j] = s * __int_as_float(e.y);
                        v[j] = xp[(size_t)e.x * 64 + lane];
                    }
#pragma unroll
                    for (int j = 0; j < 8; ++j) {
                        acc.x += w[j] * v[j].x;
                        acc.y += w[j] * v[j].y;
                    }
                }
            }
            for (; k < stop; ++k) {
                int2 e = eout[k];
                float w = s * __int_as_float(e.y);
                if (USE_BF16) {
                    unsigned d = xbp[(size_t)e.x * 64 + lane];
                    acc.x += w * __uint_as_float((d & 0xFFFFu) << 16);
                    acc.y += w * __uint_as_float(d & 0xFFFF0000u);
                } else {
                    float2 v = xp[(size_t)e.x * 64 + lane];
                    acc.x += w * v.x;
                    acc.y += w * v.y;
                }
            }
            reinterpret_cast<float2*>(out)[rb + lane] = acc;
        }
    } else {
        // correctness-only fallback (unreachable for ~1k-edge buckets)
        for (int q = 0; q < 8; ++q) {
            int lr = wave * 8 + q;
            int r = r0 + lr;
            if (r >= n_nodes) break;
            float s = sval[lr];
            int rb = r * 64;
            float2 acc = reinterpret_cast<const float2*>(x0)[rb + lane];
            if (USE_BF16) {
                unsigned dx = xbp[rb + lane];
                acc.x -= s * __uint_as_float((dx & 0xFFFFu) << 16);
                acc.y -= s * __uint_as_float(dx & 0xFFFF0000u);
            } else {
                float2 xv = xp[rb + lane];
                acc.x -= s * xv.x;
                acc.y -= s * xv.y;
            }
            for (int i = 0; i < n; ++i) {
                int2 e = epackA[begin + i];
                if ((e.x >> 17) == lr) {
                    float w = s * __int_as_float(e.y);
                    if (USE_BF16) {
                        unsigned d = xbp[(size_t)(e.x & 0x1FFFF) * 64 + lane];
                        acc.x += w * __uint_as_float((d & 0xFFFFu) << 16);
                        acc.y += w * __uint_as_float(d & 0xFFFF0000u);
                    } else {
                        float2 v = xp[(size_t)(e.x & 0x1FFFF) * 64 + lane];
                        acc.x += w * v.x;
                        acc.y += w * v.y;
                    }
                }
            }
            reinterpret_cast<float2*>(out)[rb + lane] = acc;
        }
    }
}

extern "C" void kernel_launch(void* const* d_in, const int* in_sizes, int n_in,
                              void* d_out, int out_size, void* d_ws, size_t ws_size,
                              hipStream_t stream) {
    // inputs: 0=t(unused), 1=x[N,D], 2=x0[N,D], 3=alpha[N], 4=vals[E],
    //         5=row[E](i32), 6=col[E](i32)
    const float* x     = (const float*)d_in[1];
    const float* x0    = (const float*)d_in[2];
    const float* alpha = (const float*)d_in[3];
    const float* vals  = (const float*)d_in[4];
    const int*   row   = (const int*)d_in[5];
    const int*   col   = (const int*)d_in[6];
    float* out = (float*)d_out;

    int n_nodes = in_sizes[3];
    int n_edges = in_sizes[4];
    int nb = (n_nodes + RPB - 1) / RPB;            // 1563 buckets

    // workspace layout: xb FIRST (256B-aligned -> minimal gather granules)
    size_t xb_bytes = (size_t)n_nodes * DIM * sizeof(unsigned short);
    size_t ep_bytes = (size_t)((n_edges + 3) & ~3) * sizeof(int2);
    size_t meta_bytes = (size_t)(NBMAX + NBMAX + 16 + NBMAX) * sizeof(int);
    int use_bf16 = (ws_size >= xb_bytes + ep_bytes + meta_bytes + 512) ? 1 : 0;

    unsigned short* xxb;
    int2* epackA;
    int* bhist;
    if (use_bf16) {
        xxb    = (unsigned short*)d_ws;
        epackA = (int2*)((char*)d_ws + xb_bytes);
        bhist  = (int*)((char*)epackA + ep_bytes);
    } else {
        xxb    = nullptr;
        epackA = (int2*)d_ws;
        bhist  = (int*)((char*)epackA + ep_bytes);
    }
    int* boffs = bhist + NBMAX;                    // NBMAX+16
    int* bcur  = boffs + NBMAX + 16;               // NBMAX

    hipMemsetAsync(bhist, 0, NBMAX * sizeof(int), stream);

    {
        int n4 = use_bf16 ? ((n_nodes * DIM) >> 2) : 0;
        int xg = use_bf16 ? ((n4 + 255) / 256) : 0;
        xcast_hist_kernel<<<xg + HISTB, 256, 0, stream>>>(
            x, xxb, n4, row, bhist, n_edges, nb, xg);
    }
    bucket_scan_kernel<<<1, 1024, 0, stream>>>(bhist, boffs, bcur, nb);
    {
        int grid = (n_edges + ACHUNK - 1) / ACHUNK;
        bin_kernel<<<grid, 256, 0, stream>>>(row, col, vals, bcur, epackA,
                                             n_edges, nb);
    }
    if (use_bf16) {
        fused_sort_gather_kernel<1><<<nb, 512, 0, stream>>>(
            xxb, x, x0, alpha, boffs, epackA, out, n_nodes);
    } else {
        fused_sort_gather_kernel<0><<<nb, 512, 0, stream>>>(
            xxb, x, x0, alpha, boffs, epackA, out, n_nodes);
    }
}